// Round 2
// baseline (116.519 us; speedup 1.0000x reference)
//
#include <hip/hip_runtime.h>
#include <hip/hip_bf16.h>
#include <math.h>

#define Bb 512
#define Tt 256
#define Cc 384
#define Hh 64
#define N3 192

typedef __attribute__((ext_vector_type(8))) short short8;
typedef __attribute__((ext_vector_type(4))) float float4_;

static __device__ __forceinline__ unsigned short f2bf(float f) {
  __hip_bfloat16 h = __float2bfloat16(f);
  return *reinterpret_cast<unsigned short*>(&h);
}

// ---------------- kernel 0: pack W into transposed bf16 wt[192][384] ----------------
__global__ void wtrans_kernel(const float* __restrict__ wq,
                              const float* __restrict__ wk,
                              const float* __restrict__ wv,
                              unsigned short* __restrict__ wt) {
  int n = blockIdx.x;       // 0..191 output column (q|k|v)
  int k = threadIdx.x;      // 0..383
  const float* w = (n < 64) ? wq : (n < 128) ? wk : wv;
  wt[n * Cc + k] = f2bf(w[k * Hh + (n & 63)]);
}

// ---------------- kernel 1: qkv = x @ [wq|wk|wv]  (bf16 MFMA) ----------------
#define APAD 72
#define WPAD 72
#define OSTR 204   // epilogue bounce stride (shorts): 408 B == 6 mod 32 banks

__global__ __launch_bounds__(256, 4) void proj_kernel(
    const float* __restrict__ x, const unsigned short* __restrict__ wt,
    unsigned short* __restrict__ qkv) {
  // 64*APAD + 192*WPAD = 18432 shorts = 36864 B; epilogue reuses the same
  // space as a [64][OSTR] f32->bf16 bounce tile (13056 shorts).
  __shared__ unsigned short lds[64 * APAD + 192 * WPAD];
  unsigned short* a_lds = lds;
  unsigned short* w_lds = lds + 64 * APAD;

  const int t = threadIdx.x;
  const int wid = t >> 6, lane = t & 63;
  const int fr = lane & 15, fg = lane >> 4;
  const int wr = wid >> 1, wc = wid & 1;   // 2x2 wave grid: 32 rows x 96 cols each
  const size_t m0 = (size_t)blockIdx.x * 64;

  const int ar = t >> 2, aseg = t & 3;     // A staging: 64 rows, 4 segs of 16 f32

  float4_ acc[2][6];
#pragma unroll
  for (int i = 0; i < 2; i++)
#pragma unroll
    for (int j = 0; j < 6; j++) acc[i][j] = (float4_)0.f;

  // register prefetch of the A (x) stream — the HBM-bound part
  float4_ av0, av1, av2, av3;
  {
    const float* src = x + (m0 + ar) * Cc + 0 + aseg * 16;
    av0 = *(const float4_*)(src);
    av1 = *(const float4_*)(src + 4);
    av2 = *(const float4_*)(src + 8);
    av3 = *(const float4_*)(src + 12);
  }

  for (int ks = 0; ks < 6; ks++) {
    __syncthreads();   // previous iteration's LDS consumers done
    {   // A: convert prefetched f32 regs -> bf16 LDS
      short8 w0, w1;
#pragma unroll
      for (int j = 0; j < 4; j++) {
        w0[j]     = (short)f2bf(av0[j]);
        w0[4 + j] = (short)f2bf(av1[j]);
        w1[j]     = (short)f2bf(av2[j]);
        w1[4 + j] = (short)f2bf(av3[j]);
      }
      *(short8*)(&a_lds[ar * APAD + aseg * 16])     = w0;
      *(short8*)(&a_lds[ar * APAD + aseg * 16 + 8]) = w1;
    }
    {   // W: L2-hot, load + stage in-iteration (192x64 bf16 tile)
#pragma unroll
      for (int i = 0; i < 6; i++) {
        int id = t + i * 256;
        int n = id >> 3, sg = id & 7;
        short8 v = *(const short8*)(wt + n * Cc + ks * 64 + sg * 8);
        *(short8*)(&w_lds[n * WPAD + sg * 8]) = v;
      }
    }
    if (ks < 5) {   // issue next A-tile loads; in flight across the MFMA phase
      const float* src = x + (m0 + ar) * Cc + (ks + 1) * 64 + aseg * 16;
      av0 = *(const float4_*)(src);
      av1 = *(const float4_*)(src + 4);
      av2 = *(const float4_*)(src + 8);
      av3 = *(const float4_*)(src + 12);
    }
    __syncthreads();
#pragma unroll
    for (int kk = 0; kk < 2; kk++) {
      short8 af[2], bfr[6];
#pragma unroll
      for (int mi = 0; mi < 2; mi++)
        af[mi] = *(const short8*)(&a_lds[(wr * 32 + mi * 16 + fr) * APAD + kk * 32 + fg * 8]);
#pragma unroll
      for (int ni = 0; ni < 6; ni++)
        bfr[ni] = *(const short8*)(&w_lds[(wc * 96 + ni * 16 + fr) * WPAD + kk * 32 + fg * 8]);
#pragma unroll
      for (int mi = 0; mi < 2; mi++)
#pragma unroll
        for (int ni = 0; ni < 6; ni++)
          acc[mi][ni] = __builtin_amdgcn_mfma_f32_16x16x32_bf16(af[mi], bfr[ni], acc[mi][ni], 0, 0, 0);
    }
  }

  // ---------------- epilogue: LDS bounce -> coalesced 16B stores ----------------
  __syncthreads();   // all MFMA LDS reads done before overwrite
#pragma unroll
  for (int mi = 0; mi < 2; mi++)
#pragma unroll
    for (int ni = 0; ni < 6; ni++)
#pragma unroll
      for (int r = 0; r < 4; r++) {
        int row = wr * 32 + mi * 16 + fg * 4 + r;   // D layout: col=lane&15, row=fg*4+reg
        int col = wc * 96 + ni * 16 + fr;
        lds[row * OSTR + col] = f2bf(acc[mi][ni][r]);
      }
  __syncthreads();
#pragma unroll
  for (int i = 0; i < 6; i++) {
    int id = t + i * 256;            // 64 rows x 24 short8/row = 1536 ids
    int row = id / 24, c8 = id % 24;
    short8 v = *(const short8*)(&lds[row * OSTR + c8 * 8]);
    *(short8*)(&qkv[(m0 + row) * N3 + c8 * 8]) = v;
  }
}

// ---------------- kernel 2: causal flash attention per batch ----------------
#define KPAD 72
#define VTP  264
#define PSTR 40

__global__ __launch_bounds__(256) void attn_kernel(
    const unsigned short* __restrict__ qkv, float* __restrict__ out) {
  __shared__ unsigned short k_lds[Tt * KPAD];      // 36864 B
  __shared__ unsigned short vt_lds[Hh * VTP];      // 33792 B  (V transposed: [h][t])
  __shared__ unsigned short p_lds[4 * 16 * PSTR];  // 5120 B, wave-private P tiles
  const int t = threadIdx.x;
  const int wid = t >> 6, lane = t & 63;
  const int fr = lane & 15, fg = lane >> 4;
  const int b = blockIdx.x;
  const unsigned short* base = qkv + (size_t)b * Tt * N3;

#pragma unroll
  for (int i = 0; i < 8; i++) {
    int c = t + i * 256;
    int row = c >> 3, seg = c & 7;
    short8 kv = *(const short8*)(base + row * N3 + Hh + seg * 8);
    *(short8*)(&k_lds[row * KPAD + seg * 8]) = kv;
    short8 vv = *(const short8*)(base + row * N3 + 2 * Hh + seg * 8);
#pragma unroll
    for (int j = 0; j < 8; j++)
      vt_lds[(seg * 8 + j) * VTP + row] = (unsigned short)vv[j];
  }
  __syncthreads();

  const float SC  = 0.05103103630798288f;   // 384^-0.5
  const float L2E = 1.4426950408889634f;

  int qts[4] = { wid, 7 - wid, 8 + wid, 15 - wid };  // balanced causal work
#pragma unroll 1
  for (int qi = 0; qi < 4; qi++) {
    int qt = qts[qi];
    short8 aq[2];
#pragma unroll
    for (int kk = 0; kk < 2; kk++)
      aq[kk] = *(const short8*)(base + (qt * 16 + fr) * N3 + kk * 32 + fg * 8);
    float4_ o[4] = {(float4_)0.f, (float4_)0.f, (float4_)0.f, (float4_)0.f};
    float m[4], lsum[4];
#pragma unroll
    for (int r = 0; r < 4; r++) { m[r] = -1e30f; lsum[r] = 0.f; }
    int ktmax = (qt * 16 + 15) >> 5;
    for (int kt = 0; kt <= ktmax; kt++) {
      float4_ s0 = (float4_)0.f, s1 = (float4_)0.f;
#pragma unroll
      for (int kk = 0; kk < 2; kk++) {
        short8 b0 = *(const short8*)(&k_lds[(kt * 32 + fr) * KPAD + kk * 32 + fg * 8]);
        short8 b1 = *(const short8*)(&k_lds[(kt * 32 + 16 + fr) * KPAD + kk * 32 + fg * 8]);
        s0 = __builtin_amdgcn_mfma_f32_16x16x32_bf16(aq[kk], b0, s0, 0, 0, 0);
        s1 = __builtin_amdgcn_mfma_f32_16x16x32_bf16(aq[kk], b1, s1, 0, 0, 0);
      }
      bool edge = (kt == ktmax);
#pragma unroll
      for (int r = 0; r < 4; r++) {
        int qg = qt * 16 + fg * 4 + r;
        float v0 = s0[r] * SC, v1 = s1[r] * SC;
        if (edge) {
          if (kt * 32 + fr > qg)      v0 = -1e30f;
          if (kt * 32 + 16 + fr > qg) v1 = -1e30f;
        }
        float mx = fmaxf(v0, v1);
#pragma unroll
        for (int d = 1; d < 16; d <<= 1) mx = fmaxf(mx, __shfl_xor(mx, d));
        float mn = fmaxf(m[r], mx);
        float sc = exp2f((m[r] - mn) * L2E);
        float p0 = exp2f((v0 - mn) * L2E);
        float p1 = exp2f((v1 - mn) * L2E);
        m[r] = mn;
        float ps = p0 + p1;
#pragma unroll
        for (int d = 1; d < 16; d <<= 1) ps += __shfl_xor(ps, d);
        lsum[r] = lsum[r] * sc + ps;
#pragma unroll
        for (int nt = 0; nt < 4; nt++) o[nt][r] *= sc;
        int prow = fg * 4 + r;
        p_lds[wid * 16 * PSTR + prow * PSTR + fr]      = f2bf(p0);
        p_lds[wid * 16 * PSTR + prow * PSTR + 16 + fr] = f2bf(p1);
      }
      asm volatile("s_waitcnt lgkmcnt(0)" ::: "memory");
      __builtin_amdgcn_sched_barrier(0);
      short8 pa = *(const short8*)(&p_lds[wid * 16 * PSTR + fr * PSTR + fg * 8]);
#pragma unroll
      for (int nt = 0; nt < 4; nt++) {
        short8 bv = *(const short8*)(&vt_lds[(nt * 16 + fr) * VTP + kt * 32 + fg * 8]);
        o[nt] = __builtin_amdgcn_mfma_f32_16x16x32_bf16(pa, bv, o[nt], 0, 0, 0);
      }
    }
#pragma unroll
    for (int nt = 0; nt < 4; nt++)
#pragma unroll
      for (int r = 0; r < 4; r++) {
        int row = qt * 16 + fg * 4 + r;
        out[((size_t)b * Tt + row) * Hh + nt * 16 + fr] = o[nt][r] / lsum[r];
      }
  }
}

extern "C" void kernel_launch(void* const* d_in, const int* in_sizes, int n_in,
                              void* d_out, int out_size, void* d_ws, size_t ws_size,
                              hipStream_t stream) {
  const float* x  = (const float*)d_in[0];
  const float* wq = (const float*)d_in[1];
  const float* wk = (const float*)d_in[2];
  const float* wv = (const float*)d_in[3];
  unsigned short* wt  = (unsigned short*)d_ws;
  unsigned short* qkv = wt + 192 * 384;   // 147456 B then 50.3 MB of qkv bf16
  float* out = (float*)d_out;

  hipLaunchKernelGGL(wtrans_kernel, dim3(192),  dim3(384), 0, stream, wq, wk, wv, wt);
  hipLaunchKernelGGL(proj_kernel,   dim3(2048), dim3(256), 0, stream, x, wt, qkv);
  hipLaunchKernelGGL(attn_kernel,   dim3(Bb),   dim3(256), 0, stream, qkv, out);
}

// Round 3
// 75.807 us; speedup vs baseline: 1.5370x; 1.5370x over previous
//
#include <hip/hip_runtime.h>
#include <hip/hip_bf16.h>
#include <math.h>

#define Bb 512
#define Tt 256
#define Cc 384
#define Hh 64
#define N3 192

#define APAD 72
#define WPAD 72
#define KPAD 72
#define VTP  264
#define PSTR 40

typedef __attribute__((ext_vector_type(8))) short short8;
typedef __attribute__((ext_vector_type(4))) short short4_;
typedef __attribute__((ext_vector_type(4))) float float4_;

static __device__ __forceinline__ unsigned short f2bf(float f) {
  __hip_bfloat16 h = __float2bfloat16(f);
  return *reinterpret_cast<unsigned short*>(&h);
}

// ---------------- kernel 0: pack W into transposed bf16 wt[192][384] ----------------
__global__ void wtrans_kernel(const float* __restrict__ wq,
                              const float* __restrict__ wk,
                              const float* __restrict__ wv,
                              unsigned short* __restrict__ wt) {
  int n = blockIdx.x;       // 0..191 output column (q|k|v)
  int k = threadIdx.x;      // 0..383
  const float* w = (n < 64) ? wq : (n < 128) ? wk : wv;
  wt[n * Cc + k] = f2bf(w[k * Hh + (n & 63)]);
}

// ---------------- fused kernel: per-batch QKV projection + causal flash attn ----------------
// LDS map (132 KB total):
//   a_lds  [256][APAD]  x-chunk staging (phase A); Q bf16 [seq][h] (phase B/C)
//   w_lds  [192][WPAD]  W-chunk staging (phase A); P tiles (phase C)
//   k_lds  [256][KPAD]  K bf16 [seq][h]   (persistent)
//   vt_lds [64][VTP]    V^T bf16 [h][seq] (persistent)
__global__ __launch_bounds__(512, 2) void fused_kernel(
    const float* __restrict__ x, const unsigned short* __restrict__ wt,
    float* __restrict__ out) {
  __shared__ unsigned short lds[256 * APAD + 192 * WPAD + 256 * KPAD + 64 * VTP];
  unsigned short* a_lds  = lds;
  unsigned short* w_lds  = lds + 256 * APAD;
  unsigned short* k_lds  = lds + 256 * APAD + 192 * WPAD;
  unsigned short* vt_lds = lds + 256 * APAD + 192 * WPAD + 256 * KPAD;
  unsigned short* q_lds  = a_lds;   // phase-C alias
  unsigned short* p_lds  = w_lds;   // phase-C alias (8*16*PSTR = 5120 shorts)

  const int t = threadIdx.x;
  const int wid = t >> 6, lane = t & 63;
  const int fr = lane & 15, fg = lane >> 4;
  const int wr = wid >> 1, wc = wid & 1;   // 4x2 wave grid: 64 rows x 96 cols each
  const int b = blockIdx.x;
  const float* xb = x + (size_t)b * Tt * Cc;

  // ---------------- phase A: QKV = x[b] @ W  (M=256, N=192, K=384) ----------------
  float4_ acc[4][6];
#pragma unroll
  for (int i = 0; i < 4; i++)
#pragma unroll
    for (int j = 0; j < 6; j++) acc[i][j] = (float4_)0.f;

  float4_ av[8];   // register prefetch of next x-chunk (perfectly coalesced)
#pragma unroll
  for (int i = 0; i < 8; i++) {
    int f = i * 512 + t;                     // flat float4 id in 256x64 chunk
    av[i] = *(const float4_*)(xb + (f >> 4) * Cc + 0 * 64 + (f & 15) * 4);
  }

  for (int ks = 0; ks < 6; ks++) {
    __syncthreads();   // previous iteration's LDS consumers done
    // stage A: prefetched f32 -> bf16 LDS
#pragma unroll
    for (int i = 0; i < 8; i++) {
      int f = i * 512 + t;
      short4_ pk;
#pragma unroll
      for (int j = 0; j < 4; j++) pk[j] = (short)f2bf(av[i][j]);
      *(short4_*)(&a_lds[(f >> 4) * APAD + (f & 15) * 4]) = pk;
    }
    // stage W chunk 192x64 (L2-hot)
#pragma unroll
    for (int i = 0; i < 3; i++) {
      int id = t + i * 512;
      int n = id >> 3, sg = id & 7;
      short8 v = *(const short8*)(wt + n * Cc + ks * 64 + sg * 8);
      *(short8*)(&w_lds[n * WPAD + sg * 8]) = v;
    }
    // issue next chunk's loads; in flight across the MFMA phase
    if (ks < 5) {
#pragma unroll
      for (int i = 0; i < 8; i++) {
        int f = i * 512 + t;
        av[i] = *(const float4_*)(xb + (f >> 4) * Cc + (ks + 1) * 64 + (f & 15) * 4);
      }
    }
    __syncthreads();
#pragma unroll
    for (int kk = 0; kk < 2; kk++) {
      short8 af[4], bf[6];
#pragma unroll
      for (int mi = 0; mi < 4; mi++)
        af[mi] = *(const short8*)(&a_lds[(wr * 64 + mi * 16 + fr) * APAD + kk * 32 + fg * 8]);
#pragma unroll
      for (int ni = 0; ni < 6; ni++)
        bf[ni] = *(const short8*)(&w_lds[(wc * 96 + ni * 16 + fr) * WPAD + kk * 32 + fg * 8]);
#pragma unroll
      for (int mi = 0; mi < 4; mi++)
#pragma unroll
        for (int ni = 0; ni < 6; ni++)
          acc[mi][ni] = __builtin_amdgcn_mfma_f32_16x16x32_bf16(af[mi], bf[ni], acc[mi][ni], 0, 0, 0);
    }
  }

  // ---------------- phase B: scatter QKV into attention layouts ----------------
  __syncthreads();   // last MFMA's LDS reads done before overwrite
#pragma unroll
  for (int mi = 0; mi < 4; mi++) {
    int row = wr * 64 + mi * 16 + fg * 4;   // D layout: row=fg*4+r, col=fr
#pragma unroll
    for (int ni = 0; ni < 6; ni++) {
      int col = wc * 96 + ni * 16 + fr;
      if (wc == 0 && ni < 4) {               // Q cols 0..63
#pragma unroll
        for (int r = 0; r < 4; r++) q_lds[(row + r) * APAD + col] = f2bf(acc[mi][ni][r]);
      } else if ((wc == 0) || (wc == 1 && ni < 2)) {   // K cols 64..127
#pragma unroll
        for (int r = 0; r < 4; r++) k_lds[(row + r) * KPAD + (col - 64)] = f2bf(acc[mi][ni][r]);
      } else {                               // V cols 128..191 -> transposed
        short4_ pk;
#pragma unroll
        for (int r = 0; r < 4; r++) pk[r] = (short)f2bf(acc[mi][ni][r]);
        *(short4_*)(&vt_lds[(col - 128) * VTP + row]) = pk;
      }
    }
  }
  __syncthreads();

  // ---------------- phase C: causal flash attention, all operands in LDS ----------------
  const float SC  = 0.05103103630798288f;   // 384^-0.5
  const float L2E = 1.4426950408889634f;

  int qts[2] = { wid, 15 - wid };           // balanced causal work (17 kt-steps each)
#pragma unroll 1
  for (int qi = 0; qi < 2; qi++) {
    int qt = qts[qi];
    short8 aq[2];
#pragma unroll
    for (int kk = 0; kk < 2; kk++)
      aq[kk] = *(const short8*)(&q_lds[(qt * 16 + fr) * APAD + kk * 32 + fg * 8]);
    float4_ o[4] = {(float4_)0.f, (float4_)0.f, (float4_)0.f, (float4_)0.f};
    float m[4], lsum[4];
#pragma unroll
    for (int r = 0; r < 4; r++) { m[r] = -1e30f; lsum[r] = 0.f; }
    int ktmax = (qt * 16 + 15) >> 5;
    for (int kt = 0; kt <= ktmax; kt++) {
      float4_ s0 = (float4_)0.f, s1 = (float4_)0.f;
#pragma unroll
      for (int kk = 0; kk < 2; kk++) {
        short8 b0 = *(const short8*)(&k_lds[(kt * 32 + fr) * KPAD + kk * 32 + fg * 8]);
        short8 b1 = *(const short8*)(&k_lds[(kt * 32 + 16 + fr) * KPAD + kk * 32 + fg * 8]);
        s0 = __builtin_amdgcn_mfma_f32_16x16x32_bf16(aq[kk], b0, s0, 0, 0, 0);
        s1 = __builtin_amdgcn_mfma_f32_16x16x32_bf16(aq[kk], b1, s1, 0, 0, 0);
      }
      bool edge = (kt == ktmax);
#pragma unroll
      for (int r = 0; r < 4; r++) {
        int qg = qt * 16 + fg * 4 + r;
        float v0 = s0[r] * SC, v1 = s1[r] * SC;
        if (edge) {
          if (kt * 32 + fr > qg)      v0 = -1e30f;
          if (kt * 32 + 16 + fr > qg) v1 = -1e30f;
        }
        float mx = fmaxf(v0, v1);
#pragma unroll
        for (int d = 1; d < 16; d <<= 1) mx = fmaxf(mx, __shfl_xor(mx, d));
        float mn = fmaxf(m[r], mx);
        float sc = exp2f((m[r] - mn) * L2E);
        float p0 = exp2f((v0 - mn) * L2E);
        float p1 = exp2f((v1 - mn) * L2E);
        m[r] = mn;
        float ps = p0 + p1;
#pragma unroll
        for (int d = 1; d < 16; d <<= 1) ps += __shfl_xor(ps, d);
        lsum[r] = lsum[r] * sc + ps;
#pragma unroll
        for (int nt = 0; nt < 4; nt++) o[nt][r] *= sc;
        int prow = fg * 4 + r;
        p_lds[wid * 16 * PSTR + prow * PSTR + fr]      = f2bf(p0);
        p_lds[wid * 16 * PSTR + prow * PSTR + 16 + fr] = f2bf(p1);
      }
      asm volatile("s_waitcnt lgkmcnt(0)" ::: "memory");
      __builtin_amdgcn_sched_barrier(0);
      short8 pa = *(const short8*)(&p_lds[wid * 16 * PSTR + fr * PSTR + fg * 8]);
#pragma unroll
      for (int nt = 0; nt < 4; nt++) {
        short8 bv = *(const short8*)(&vt_lds[(nt * 16 + fr) * VTP + kt * 32 + fg * 8]);
        o[nt] = __builtin_amdgcn_mfma_f32_16x16x32_bf16(pa, bv, o[nt], 0, 0, 0);
      }
    }
#pragma unroll
    for (int nt = 0; nt < 4; nt++)
#pragma unroll
      for (int r = 0; r < 4; r++) {
        int row = qt * 16 + fg * 4 + r;
        out[((size_t)b * Tt + row) * Hh + nt * 16 + fr] = o[nt][r] / lsum[r];
      }
  }
}

extern "C" void kernel_launch(void* const* d_in, const int* in_sizes, int n_in,
                              void* d_out, int out_size, void* d_ws, size_t ws_size,
                              hipStream_t stream) {
  const float* x  = (const float*)d_in[0];
  const float* wq = (const float*)d_in[1];
  const float* wk = (const float*)d_in[2];
  const float* wv = (const float*)d_in[3];
  unsigned short* wt = (unsigned short*)d_ws;   // 192*384 bf16
  float* out = (float*)d_out;

  hipLaunchKernelGGL(wtrans_kernel, dim3(192), dim3(384), 0, stream, wq, wk, wv, wt);
  hipLaunchKernelGGL(fused_kernel,  dim3(Bb),  dim3(512), 0, stream, x, wt, out);
}